// Round 1
// baseline (260.447 us; speedup 1.0000x reference)
//
#include <hip/hip_runtime.h>
#include <hip/hip_bf16.h>

// Problem constants (AFT_FULL): x (B=8, C=128, H*W*D = N=4096)
#define BB 8
#define CC 128
#define NN 4096

typedef __bf16 bf16x8 __attribute__((ext_vector_type(8)));
typedef float f32x4 __attribute__((ext_vector_type(4)));

static __device__ __forceinline__ unsigned short f2bf(float f) {
  __hip_bfloat16 h = __float2bfloat16(f);
  return __builtin_bit_cast(unsigned short, h);
}

// ---------------------------------------------------------------------------
// Kernel 1: QKV projections (fp32 vector ALU).
// out layouts: qbuf[(b*C+co)][n] fp32 ; ek_bf/ekv_bf[(b*C+co)][n] bf16.
// Thread owns one column n: caches inp column x[b,:,n] in 128 VGPRs, then
// dots against 32 weight rows (co-quarter per blockIdx.y) for all 3 matrices.
// ---------------------------------------------------------------------------
__global__ __launch_bounds__(256) void qkv_kernel(
    const float* __restrict__ x,
    const float* __restrict__ Wq, const float* __restrict__ bq,
    const float* __restrict__ Wk, const float* __restrict__ bk,
    const float* __restrict__ Wv, const float* __restrict__ bv,
    float* __restrict__ qout,
    unsigned short* __restrict__ ekv_bf,
    unsigned short* __restrict__ ek_bf)
{
  const int n   = blockIdx.x * 256 + threadIdx.x;
  const int co0 = blockIdx.y * 32;
  const int b   = blockIdx.z;

  const float* xb = x + ((size_t)b * CC) * NN + n;
  float xv[CC];
#pragma unroll
  for (int c = 0; c < CC; ++c) xv[c] = xb[(size_t)c * NN];

  for (int i = 0; i < 32; ++i) {
    const int co = co0 + i;
    const float* wq = Wq + (size_t)co * CC;
    const float* wk = Wk + (size_t)co * CC;
    const float* wv = Wv + (size_t)co * CC;
    float aq = bq[co], ak = bk[co], av = bv[co];
#pragma unroll
    for (int c = 0; c < CC; ++c) {
      aq = fmaf(xv[c], wq[c], aq);
      ak = fmaf(xv[c], wk[c], ak);
      av = fmaf(xv[c], wv[c], av);
    }
    const float ekf = __expf(ak);
    const size_t o = ((size_t)(b * CC + co)) * NN + n;
    qout[o]   = aq;
    ek_bf[o]  = f2bf(ekf);
    ekv_bf[o] = f2bf(ekf * av);
  }
}

// ---------------------------------------------------------------------------
// Kernel 2: eB = bf16(exp(pos_bias)), N*N elements, vectorized.
// ---------------------------------------------------------------------------
__global__ __launch_bounds__(256) void expb_kernel(
    const float* __restrict__ pb, unsigned short* __restrict__ eb)
{
  const size_t total = (size_t)NN * NN / 4;
  const float4* p4 = (const float4*)pb;
  uint2* o4 = (uint2*)eb;
  const size_t stride = (size_t)gridDim.x * blockDim.x;
  for (size_t i = (size_t)blockIdx.x * blockDim.x + threadIdx.x; i < total; i += stride) {
    float4 v = p4[i];
    union { unsigned short s[4]; uint2 u; } r;
    r.s[0] = f2bf(__expf(v.x));
    r.s[1] = f2bf(__expf(v.y));
    r.s[2] = f2bf(__expf(v.z));
    r.s[3] = f2bf(__expf(v.w));
    o4[i] = r.u;
  }
}

// ---------------------------------------------------------------------------
// Kernel 3: bf16 MFMA GEMM, m97 structure.
// A: M x K row-major bf16 (rows = [ekv ; ek], M=2048, K=4096)
// Bt: N x K row-major bf16 (= eB[t][s], N=4096)
// C[m][t] = sum_s A[m][s] * Bt[t][s], fp32.
// 128x128 tile, BK=32, 4 waves (2x2), 16x16x32 MFMA, global_load_lds(16B).
// ---------------------------------------------------------------------------
#define BM 128
#define BN 128
#define BK 32

__global__ __launch_bounds__(256) void gemm_bt(
    const unsigned short* __restrict__ A,
    const unsigned short* __restrict__ Bt,
    float* __restrict__ C, const int M, const int N, const int K)
{
  __shared__ unsigned short As[BM * BK];
  __shared__ unsigned short Bs[BN * BK];

  const int tid  = threadIdx.x;
  const int m0   = blockIdx.x * BM;
  const int n0   = blockIdx.y * BN;
  const int wid  = tid >> 6, lane = tid & 63;
  const int wr   = wid >> 1, wc = wid & 1;
  const int fr   = lane & 15, kq = lane >> 4;

  f32x4 acc[4][4] = {};

  for (int k0 = 0; k0 < K; k0 += BK) {
    // stage A tile: 512 chunks of 16B; chunk s -> row s>>2, k-block s&3.
    // LDS dest is lane-consecutive (wave-uniform base + lane*16) as required.
#pragma unroll
    for (int i = 0; i < 2; ++i) {
      const int s = tid + i * 256;
      const int row = s >> 2, kb = s & 3;
      const unsigned short* g = A + (size_t)(m0 + row) * K + (k0 + kb * 8);
      __builtin_amdgcn_global_load_lds(
          (const __attribute__((address_space(1))) void*)g,
          (__attribute__((address_space(3))) void*)&As[s * 8], 16, 0, 0);
    }
#pragma unroll
    for (int i = 0; i < 2; ++i) {
      const int s = tid + i * 256;
      const int row = s >> 2, kb = s & 3;
      const unsigned short* g = Bt + (size_t)(n0 + row) * K + (k0 + kb * 8);
      __builtin_amdgcn_global_load_lds(
          (const __attribute__((address_space(1))) void*)g,
          (__attribute__((address_space(3))) void*)&Bs[s * 8], 16, 0, 0);
    }
    __syncthreads();

    bf16x8 af[4], bfr[4];
#pragma unroll
    for (int m = 0; m < 4; ++m)
      af[m] = *reinterpret_cast<const bf16x8*>(&As[(wr * 64 + m * 16 + fr) * BK + kq * 8]);
#pragma unroll
    for (int n = 0; n < 4; ++n)
      bfr[n] = *reinterpret_cast<const bf16x8*>(&Bs[(wc * 64 + n * 16 + fr) * BK + kq * 8]);

#pragma unroll
    for (int m = 0; m < 4; ++m)
#pragma unroll
      for (int n = 0; n < 4; ++n)
        acc[m][n] = __builtin_amdgcn_mfma_f32_16x16x32_bf16(af[m], bfr[n], acc[m][n], 0, 0, 0);

    __syncthreads();
  }

  // C/D layout (m89-verified): col = lane&15, row = (lane>>4)*4 + j
#pragma unroll
  for (int m = 0; m < 4; ++m)
#pragma unroll
    for (int n = 0; n < 4; ++n) {
      const int row0 = m0 + wr * 64 + m * 16 + kq * 4;
      const int col  = n0 + wc * 64 + n * 16 + fr;
#pragma unroll
      for (int j = 0; j < 4; ++j)
        C[(size_t)(row0 + j) * N + col] = acc[m][n][j];
    }
}

// ---------------------------------------------------------------------------
// Kernel 4: out = sigmoid(q) * num / den, all in (b*C+c, t) layout.
// ---------------------------------------------------------------------------
__global__ __launch_bounds__(256) void epilogue_kernel(
    const float* __restrict__ q,
    const float* __restrict__ outnd,
    float* __restrict__ out)
{
  const size_t total = (size_t)BB * CC * NN / 4;
  const float4* q4   = (const float4*)q;
  const float4* num4 = (const float4*)outnd;
  const float4* den4 = (const float4*)(outnd + (size_t)BB * CC * NN);
  float4* o4 = (float4*)out;
  const size_t stride = (size_t)gridDim.x * blockDim.x;
  for (size_t i = (size_t)blockIdx.x * blockDim.x + threadIdx.x; i < total; i += stride) {
    float4 qv = q4[i], nv = num4[i], dv = den4[i];
    float4 r;
    r.x = (1.0f / (1.0f + __expf(-qv.x))) * nv.x / dv.x;
    r.y = (1.0f / (1.0f + __expf(-qv.y))) * nv.y / dv.y;
    r.z = (1.0f / (1.0f + __expf(-qv.z))) * nv.z / dv.z;
    r.w = (1.0f / (1.0f + __expf(-qv.w))) * nv.w / dv.w;
    o4[i] = r;
  }
}

// ---------------------------------------------------------------------------
// Workspace layout (bytes):
//   [0, 16MiB)          : Abf  = bf16 [2048][4096]  (ekv rows 0..1023, ek rows 1024..2047)
//   [16MiB, 48MiB)      : eBbf = bf16 [4096][4096]
//   [48MiB, 80MiB)      : OutND = f32 [2048][4096]  (num rows 0..1023, den rows 1024..2047)
//   [80MiB, 96MiB)      : qbuf = f32 [1024][4096]
// total = 100,663,296 bytes
// ---------------------------------------------------------------------------
extern "C" void kernel_launch(void* const* d_in, const int* in_sizes, int n_in,
                              void* d_out, int out_size, void* d_ws, size_t ws_size,
                              hipStream_t stream) {
  const float* x  = (const float*)d_in[0];
  const float* Wq = (const float*)d_in[1];
  const float* bq = (const float*)d_in[2];
  const float* Wk = (const float*)d_in[3];
  const float* bk = (const float*)d_in[4];
  const float* Wv = (const float*)d_in[5];
  const float* bv = (const float*)d_in[6];
  const float* pb = (const float*)d_in[7];
  float* out = (float*)d_out;

  char* ws = (char*)d_ws;
  unsigned short* Abf   = (unsigned short*)ws;
  unsigned short* eBbf  = (unsigned short*)(ws + (size_t)16777216);
  float*          OutND = (float*)(ws + (size_t)16777216 + 33554432);
  float*          qbuf  = (float*)(ws + (size_t)16777216 + 33554432 + 33554432);

  unsigned short* ekv_bf = Abf;                          // rows 0..1023  -> numerator
  unsigned short* ek_bf  = Abf + (size_t)1024 * NN;      // rows 1024..2047 -> denominator

  hipLaunchKernelGGL(qkv_kernel, dim3(NN / 256, 4, BB), dim3(256), 0, stream,
                     x, Wq, bq, Wk, bk, Wv, bv, qbuf, ekv_bf, ek_bf);
  hipLaunchKernelGGL(expb_kernel, dim3(2048), dim3(256), 0, stream, pb, eBbf);
  hipLaunchKernelGGL(gemm_bt, dim3(2048 / BM, NN / BN), dim3(256), 0, stream,
                     Abf, eBbf, OutND, 2048, NN, NN);
  hipLaunchKernelGGL(epilogue_kernel, dim3(2048), dim3(256), 0, stream,
                     qbuf, OutND, out);
}

// Round 2
// 165.770 us; speedup vs baseline: 1.5711x; 1.5711x over previous
//
#include <hip/hip_runtime.h>
#include <hip/hip_bf16.h>

// Problem constants (AFT_FULL): x (B=8, C=128, H*W*D = N=4096)
#define BB 8
#define CC 128
#define NN 4096

typedef __bf16 bf16x8 __attribute__((ext_vector_type(8)));
typedef float f32x4 __attribute__((ext_vector_type(4)));

static __device__ __forceinline__ unsigned short f2bf(float f) {
  __hip_bfloat16 h = __float2bfloat16(f);
  return __builtin_bit_cast(unsigned short, h);
}
static __device__ __forceinline__ float bf2f(unsigned short u) {
  return __builtin_bit_cast(float, (unsigned int)u << 16);
}

// ---------------------------------------------------------------------------
// Kernel 1: QKV via MFMA. One block per (n-tile of 128, g in {q,k,v}, b).
// C_g[co][n] = sum_c W_g[co][c] * x[b][c][n0+n]  (+ bias)
// Stage x transposed -> XT[n][c] bf16 (XOR-swizzled, G4 fix for the 32-way
// conflict of linear [*][128] rows), W_g -> WT[co][c] same swizzle.
// K=128 entirely resident: 4 K-steps x 16 MFMA, no double-buffer.
// Fused epilogue: g=0 -> sigmoid(q) fp32; g=1 -> exp(k) bf16 (big-GEMM A
// denominator rows); g=2 -> v bf16.
// ---------------------------------------------------------------------------
__global__ __launch_bounds__(256) void qkv_mfma(
    const float* __restrict__ x,
    const float* __restrict__ Wq, const float* __restrict__ bq,
    const float* __restrict__ Wk, const float* __restrict__ bk,
    const float* __restrict__ Wv, const float* __restrict__ bv,
    float* __restrict__ sq,
    unsigned short* __restrict__ ek_bf,
    unsigned short* __restrict__ v_bf)
{
  __shared__ __align__(16) unsigned short XT[128 * 128];
  __shared__ __align__(16) unsigned short WT[128 * 128];

  const int tid = threadIdx.x;
  const int n0  = blockIdx.x * 128;
  const int g   = blockIdx.y;   // 0=q, 1=k, 2=v (uniform per block)
  const int b   = blockIdx.z;

  const float* W    = (g == 0) ? Wq : (g == 1) ? Wk : Wv;
  const float* bias = (g == 0) ? bq : (g == 1) ? bk : bv;

  // ---- stage x^T: XT[n][c] = bf16(x[b][c][n0+n]), swizzle byte^=((n&7)<<4)
  {
    const int c   = tid & 127;
    const int grp = tid >> 7;                      // 0,1
    const float* xrow = x + ((size_t)(b * CC + c)) * NN + n0;
#pragma unroll
    for (int i = 0; i < 16; ++i) {
      const int n4 = grp * 16 + i;                 // float4 index along n
      const float4 v4 = *(const float4*)(xrow + n4 * 4);
      const float vv[4] = {v4.x, v4.y, v4.z, v4.w};
#pragma unroll
      for (int j = 0; j < 4; ++j) {
        const int n = n4 * 4 + j;
        const int byte = (2 * (n * 128 + c)) ^ ((n & 7) << 4);
        *(unsigned short*)((char*)XT + byte) = f2bf(vv[j]);
      }
    }
  }
  // ---- stage W_g: WT[co][c] = bf16(W[co][c]), swizzle byte^=((co&7)<<4)
  {
    const int c   = tid & 127;
    const int grp = tid >> 7;
#pragma unroll
    for (int i = 0; i < 64; ++i) {
      const int co = grp * 64 + i;
      const float wv = W[(size_t)co * CC + c];
      const int byte = (2 * (co * 128 + c)) ^ ((co & 7) << 4);
      *(unsigned short*)((char*)WT + byte) = f2bf(wv);
    }
  }
  __syncthreads();

  const int lane = tid & 63, wid = tid >> 6;
  const int wr = wid >> 1, wc = wid & 1;
  const int fr = lane & 15, kq = lane >> 4;

  f32x4 acc[4][4] = {};
#pragma unroll
  for (int k0 = 0; k0 < 128; k0 += 32) {
    bf16x8 af[4], bfr[4];
#pragma unroll
    for (int m = 0; m < 4; ++m) {
      const int r = wr * 64 + m * 16 + fr;
      const int byte = (2 * (r * 128 + k0 + kq * 8)) ^ ((r & 7) << 4);
      af[m] = *(const bf16x8*)((const char*)WT + byte);
    }
#pragma unroll
    for (int n = 0; n < 4; ++n) {
      const int r = wc * 64 + n * 16 + fr;
      const int byte = (2 * (r * 128 + k0 + kq * 8)) ^ ((r & 7) << 4);
      bfr[n] = *(const bf16x8*)((const char*)XT + byte);
    }
#pragma unroll
    for (int m = 0; m < 4; ++m)
#pragma unroll
      for (int n = 0; n < 4; ++n)
        acc[m][n] = __builtin_amdgcn_mfma_f32_16x16x32_bf16(af[m], bfr[n], acc[m][n], 0, 0, 0);
  }

  // C/D layout (m89): col = lane&15, row = kq*4 + j
#pragma unroll
  for (int m = 0; m < 4; ++m)
#pragma unroll
    for (int n = 0; n < 4; ++n) {
      const int row0 = wr * 64 + m * 16 + kq * 4;
      const int col  = n0 + wc * 64 + n * 16 + fr;
#pragma unroll
      for (int j = 0; j < 4; ++j) {
        const int co = row0 + j;
        const float val = acc[m][n][j] + bias[co];
        const size_t o = ((size_t)(b * CC + co)) * NN + col;
        if (g == 0)      sq[o]    = 1.0f / (1.0f + __expf(-val));
        else if (g == 1) ek_bf[o] = f2bf(__expf(val));
        else             v_bf[o]  = f2bf(val);
      }
    }
}

// ---------------------------------------------------------------------------
// Kernel 1b: ekv = ek * v (bf16 elementwise, uint4 = 8 bf16 per load)
// ---------------------------------------------------------------------------
static __device__ __forceinline__ unsigned int mul2bf(unsigned int a, unsigned int b) {
  const float alo = __builtin_bit_cast(float, a << 16);
  const float ahi = __builtin_bit_cast(float, a & 0xffff0000u);
  const float blo = __builtin_bit_cast(float, b << 16);
  const float bhi = __builtin_bit_cast(float, b & 0xffff0000u);
  return (unsigned int)f2bf(alo * blo) | ((unsigned int)f2bf(ahi * bhi) << 16);
}

__global__ __launch_bounds__(256) void ekv_kernel(
    const unsigned short* __restrict__ ek_bf,
    const unsigned short* __restrict__ v_bf,
    unsigned short* __restrict__ ekv_bf)
{
  const size_t total = (size_t)BB * CC * NN / 8;   // uint4 count
  const uint4* e8 = (const uint4*)ek_bf;
  const uint4* v8 = (const uint4*)v_bf;
  uint4* o8 = (uint4*)ekv_bf;
  const size_t stride = (size_t)gridDim.x * blockDim.x;
  for (size_t i = (size_t)blockIdx.x * blockDim.x + threadIdx.x; i < total; i += stride) {
    const uint4 e = e8[i], v = v8[i];
    uint4 r;
    r.x = mul2bf(e.x, v.x);
    r.y = mul2bf(e.y, v.y);
    r.z = mul2bf(e.z, v.z);
    r.w = mul2bf(e.w, v.w);
    o8[i] = r;
  }
}

// ---------------------------------------------------------------------------
// Kernel 2: eB = bf16(exp(pos_bias)), N*N elements, vectorized.
// ---------------------------------------------------------------------------
__global__ __launch_bounds__(256) void expb_kernel(
    const float* __restrict__ pb, unsigned short* __restrict__ eb)
{
  const size_t total = (size_t)NN * NN / 4;
  const float4* p4 = (const float4*)pb;
  uint2* o4 = (uint2*)eb;
  const size_t stride = (size_t)gridDim.x * blockDim.x;
  for (size_t i = (size_t)blockIdx.x * blockDim.x + threadIdx.x; i < total; i += stride) {
    float4 v = p4[i];
    union { unsigned short s[4]; uint2 u; } r;
    r.s[0] = f2bf(__expf(v.x));
    r.s[1] = f2bf(__expf(v.y));
    r.s[2] = f2bf(__expf(v.z));
    r.s[3] = f2bf(__expf(v.w));
    o4[i] = r.u;
  }
}

// ---------------------------------------------------------------------------
// Kernel 3: bf16 MFMA GEMM, m97 structure (unchanged from R1, passed).
// A: 2048 x 4096 row-major bf16 (rows = [ekv ; ek])
// Bt: 4096 x 4096 row-major bf16 (= eB[t][s])
// C[m][t] = sum_s A[m][s] * Bt[t][s], fp32.
// ---------------------------------------------------------------------------
#define BM 128
#define BN 128
#define BK 32

__global__ __launch_bounds__(256) void gemm_bt(
    const unsigned short* __restrict__ A,
    const unsigned short* __restrict__ Bt,
    float* __restrict__ C, const int M, const int N, const int K)
{
  __shared__ unsigned short As[BM * BK];
  __shared__ unsigned short Bs[BN * BK];

  const int tid  = threadIdx.x;
  const int m0   = blockIdx.x * BM;
  const int n0   = blockIdx.y * BN;
  const int wid  = tid >> 6, lane = tid & 63;
  const int wr   = wid >> 1, wc = wid & 1;
  const int fr   = lane & 15, kq = lane >> 4;

  f32x4 acc[4][4] = {};

  for (int k0 = 0; k0 < K; k0 += BK) {
#pragma unroll
    for (int i = 0; i < 2; ++i) {
      const int s = tid + i * 256;
      const int row = s >> 2, kb = s & 3;
      const unsigned short* g = A + (size_t)(m0 + row) * K + (k0 + kb * 8);
      __builtin_amdgcn_global_load_lds(
          (const __attribute__((address_space(1))) void*)g,
          (__attribute__((address_space(3))) void*)&As[s * 8], 16, 0, 0);
    }
#pragma unroll
    for (int i = 0; i < 2; ++i) {
      const int s = tid + i * 256;
      const int row = s >> 2, kb = s & 3;
      const unsigned short* g = Bt + (size_t)(n0 + row) * K + (k0 + kb * 8);
      __builtin_amdgcn_global_load_lds(
          (const __attribute__((address_space(1))) void*)g,
          (__attribute__((address_space(3))) void*)&Bs[s * 8], 16, 0, 0);
    }
    __syncthreads();

    bf16x8 af[4], bfr[4];
#pragma unroll
    for (int m = 0; m < 4; ++m)
      af[m] = *reinterpret_cast<const bf16x8*>(&As[(wr * 64 + m * 16 + fr) * BK + kq * 8]);
#pragma unroll
    for (int n = 0; n < 4; ++n)
      bfr[n] = *reinterpret_cast<const bf16x8*>(&Bs[(wc * 64 + n * 16 + fr) * BK + kq * 8]);

#pragma unroll
    for (int m = 0; m < 4; ++m)
#pragma unroll
      for (int n = 0; n < 4; ++n)
        acc[m][n] = __builtin_amdgcn_mfma_f32_16x16x32_bf16(af[m], bfr[n], acc[m][n], 0, 0, 0);

    __syncthreads();
  }

#pragma unroll
  for (int m = 0; m < 4; ++m)
#pragma unroll
    for (int n = 0; n < 4; ++n) {
      const int row0 = m0 + wr * 64 + m * 16 + kq * 4;
      const int col  = n0 + wc * 64 + n * 16 + fr;
#pragma unroll
      for (int j = 0; j < 4; ++j)
        C[(size_t)(row0 + j) * N + col] = acc[m][n][j];
    }
}

// ---------------------------------------------------------------------------
// Kernel 4: out = sq * num / den   (sigmoid already applied in qkv_mfma)
// ---------------------------------------------------------------------------
__global__ __launch_bounds__(256) void epilogue_kernel(
    const float* __restrict__ sq,
    const float* __restrict__ outnd,
    float* __restrict__ out)
{
  const size_t total = (size_t)BB * CC * NN / 4;
  const float4* q4   = (const float4*)sq;
  const float4* num4 = (const float4*)outnd;
  const float4* den4 = (const float4*)(outnd + (size_t)BB * CC * NN);
  float4* o4 = (float4*)out;
  const size_t stride = (size_t)gridDim.x * blockDim.x;
  for (size_t i = (size_t)blockIdx.x * blockDim.x + threadIdx.x; i < total; i += stride) {
    float4 qv = q4[i], nv = num4[i], dv = den4[i];
    float4 r;
    r.x = qv.x * nv.x / dv.x;
    r.y = qv.y * nv.y / dv.y;
    r.z = qv.z * nv.z / dv.z;
    r.w = qv.w * nv.w / dv.w;
    o4[i] = r;
  }
}

// ---------------------------------------------------------------------------
// Workspace (96 MiB, same total as the known-good R1 layout):
//   [0, 16MiB)     : Abf  = bf16 [2048][4096]  (rows 0..1023 ekv, 1024..2047 ek)
//   [16MiB, 48MiB) : eBbf = bf16 [4096][4096]
//   [48MiB, 80MiB) : OutND = f32 [2048][4096]; v_bf bf16[1024][4096] ALIASES
//                    its first 8MiB (read by ekv_kernel before gemm writes)
//   [80MiB, 96MiB) : sq = f32 [1024][4096]
// ---------------------------------------------------------------------------
extern "C" void kernel_launch(void* const* d_in, const int* in_sizes, int n_in,
                              void* d_out, int out_size, void* d_ws, size_t ws_size,
                              hipStream_t stream) {
  const float* x  = (const float*)d_in[0];
  const float* Wq = (const float*)d_in[1];
  const float* bq = (const float*)d_in[2];
  const float* Wk = (const float*)d_in[3];
  const float* bk = (const float*)d_in[4];
  const float* Wv = (const float*)d_in[5];
  const float* bv = (const float*)d_in[6];
  const float* pb = (const float*)d_in[7];
  float* out = (float*)d_out;

  char* ws = (char*)d_ws;
  unsigned short* Abf   = (unsigned short*)ws;
  unsigned short* eBbf  = (unsigned short*)(ws + (size_t)16777216);
  float*          OutND = (float*)(ws + (size_t)16777216 + 33554432);
  float*          sqb   = (float*)(ws + (size_t)16777216 + 33554432 + 33554432);

  unsigned short* ekv_bf = Abf;                       // rows 0..1023  -> numerator
  unsigned short* ek_bf  = Abf + (size_t)1024 * NN;   // rows 1024..2047 -> denominator
  unsigned short* v_bf   = (unsigned short*)OutND;    // aliases OutND head (safe: read before gemm)

  hipLaunchKernelGGL(qkv_mfma, dim3(NN / 128, 3, BB), dim3(256), 0, stream,
                     x, Wq, bq, Wk, bk, Wv, bv, sqb, ek_bf, v_bf);
  hipLaunchKernelGGL(ekv_kernel, dim3(1024), dim3(256), 0, stream,
                     ek_bf, v_bf, ekv_bf);
  hipLaunchKernelGGL(expb_kernel, dim3(2048), dim3(256), 0, stream, pb, eBbf);
  hipLaunchKernelGGL(gemm_bt, dim3(2048 / BM, NN / BN), dim3(256), 0, stream,
                     Abf, eBbf, OutND, 2048, NN, NN);
  hipLaunchKernelGGL(epilogue_kernel, dim3(2048), dim3(256), 0, stream,
                     sqb, OutND, out);
}

// Round 3
// 165.244 us; speedup vs baseline: 1.5761x; 1.0032x over previous
//
#include <hip/hip_runtime.h>
#include <hip/hip_bf16.h>

// Problem constants (AFT_FULL): x (B=8, C=128, H*W*D = N=4096)
#define BB 8
#define CC 128
#define NN 4096

typedef __bf16 bf16x8 __attribute__((ext_vector_type(8)));
typedef float f32x4 __attribute__((ext_vector_type(4)));

static __device__ __forceinline__ unsigned short f2bf(float f) {
  __hip_bfloat16 h = __float2bfloat16(f);
  return __builtin_bit_cast(unsigned short, h);
}
static __device__ __forceinline__ float bf2f(unsigned short u) {
  return __builtin_bit_cast(float, (unsigned int)u << 16);
}

// ---------------------------------------------------------------------------
// Kernel 1: QKV via MFMA (unchanged structure from R2, passed).
// g=0 -> sigmoid(q) fp32 straight into d_out; g=1 -> exp(k) bf16; g=2 -> v bf16.
// ---------------------------------------------------------------------------
__global__ __launch_bounds__(256) void qkv_mfma(
    const float* __restrict__ x,
    const float* __restrict__ Wq, const float* __restrict__ bq,
    const float* __restrict__ Wk, const float* __restrict__ bk,
    const float* __restrict__ Wv, const float* __restrict__ bv,
    float* __restrict__ sq,
    unsigned short* __restrict__ ek_bf,
    unsigned short* __restrict__ v_bf)
{
  __shared__ __align__(16) unsigned short XT[128 * 128];
  __shared__ __align__(16) unsigned short WT[128 * 128];

  const int tid = threadIdx.x;
  const int n0  = blockIdx.x * 128;
  const int g   = blockIdx.y;   // 0=q, 1=k, 2=v (uniform per block)
  const int b   = blockIdx.z;

  const float* W    = (g == 0) ? Wq : (g == 1) ? Wk : Wv;
  const float* bias = (g == 0) ? bq : (g == 1) ? bk : bv;

  // ---- stage x^T: XT[n][c] = bf16(x[b][c][n0+n]), swizzle byte^=((n&7)<<4)
  {
    const int c   = tid & 127;
    const int grp = tid >> 7;                      // 0,1
    const float* xrow = x + ((size_t)(b * CC + c)) * NN + n0;
#pragma unroll
    for (int i = 0; i < 16; ++i) {
      const int n4 = grp * 16 + i;                 // float4 index along n
      const float4 v4 = *(const float4*)(xrow + n4 * 4);
      const float vv[4] = {v4.x, v4.y, v4.z, v4.w};
#pragma unroll
      for (int j = 0; j < 4; ++j) {
        const int n = n4 * 4 + j;
        const int byte = (2 * (n * 128 + c)) ^ ((n & 7) << 4);
        *(unsigned short*)((char*)XT + byte) = f2bf(vv[j]);
      }
    }
  }
  // ---- stage W_g: WT[co][c] = bf16(W[co][c]), swizzle byte^=((co&7)<<4)
  {
    const int c   = tid & 127;
    const int grp = tid >> 7;
#pragma unroll
    for (int i = 0; i < 64; ++i) {
      const int co = grp * 64 + i;
      const float wv = W[(size_t)co * CC + c];
      const int byte = (2 * (co * 128 + c)) ^ ((co & 7) << 4);
      *(unsigned short*)((char*)WT + byte) = f2bf(wv);
    }
  }
  __syncthreads();

  const int lane = tid & 63, wid = tid >> 6;
  const int wr = wid >> 1, wc = wid & 1;
  const int fr = lane & 15, kq = lane >> 4;

  f32x4 acc[4][4] = {};
#pragma unroll
  for (int k0 = 0; k0 < 128; k0 += 32) {
    bf16x8 af[4], bfr[4];
#pragma unroll
    for (int m = 0; m < 4; ++m) {
      const int r = wr * 64 + m * 16 + fr;
      const int byte = (2 * (r * 128 + k0 + kq * 8)) ^ ((r & 7) << 4);
      af[m] = *(const bf16x8*)((const char*)WT + byte);
    }
#pragma unroll
    for (int n = 0; n < 4; ++n) {
      const int r = wc * 64 + n * 16 + fr;
      const int byte = (2 * (r * 128 + k0 + kq * 8)) ^ ((r & 7) << 4);
      bfr[n] = *(const bf16x8*)((const char*)XT + byte);
    }
#pragma unroll
    for (int m = 0; m < 4; ++m)
#pragma unroll
      for (int n = 0; n < 4; ++n)
        acc[m][n] = __builtin_amdgcn_mfma_f32_16x16x32_bf16(af[m], bfr[n], acc[m][n], 0, 0, 0);
  }

  // C/D layout (m89): col = lane&15, row = kq*4 + j
#pragma unroll
  for (int m = 0; m < 4; ++m)
#pragma unroll
    for (int n = 0; n < 4; ++n) {
      const int row0 = wr * 64 + m * 16 + kq * 4;
      const int col  = n0 + wc * 64 + n * 16 + fr;
#pragma unroll
      for (int j = 0; j < 4; ++j) {
        const int co = row0 + j;
        const float val = acc[m][n][j] + bias[co];
        const size_t o = ((size_t)(b * CC + co)) * NN + col;
        if (g == 0)      sq[o]    = 1.0f / (1.0f + __expf(-val));
        else if (g == 1) ek_bf[o] = f2bf(__expf(val));
        else             v_bf[o]  = f2bf(val);
      }
    }
}

// ---------------------------------------------------------------------------
// Kernel 1b: ekv = ek * v (bf16 elementwise, uint4 = 8 bf16 per load)
// ---------------------------------------------------------------------------
static __device__ __forceinline__ unsigned int mul2bf(unsigned int a, unsigned int b) {
  const float alo = __builtin_bit_cast(float, a << 16);
  const float ahi = __builtin_bit_cast(float, a & 0xffff0000u);
  const float blo = __builtin_bit_cast(float, b << 16);
  const float bhi = __builtin_bit_cast(float, b & 0xffff0000u);
  return (unsigned int)f2bf(alo * blo) | ((unsigned int)f2bf(ahi * bhi) << 16);
}

__global__ __launch_bounds__(256) void ekv_kernel(
    const unsigned short* __restrict__ ek_bf,
    const unsigned short* __restrict__ v_bf,
    unsigned short* __restrict__ ekv_bf)
{
  const size_t total = (size_t)BB * CC * NN / 8;   // uint4 count
  const uint4* e8 = (const uint4*)ek_bf;
  const uint4* v8 = (const uint4*)v_bf;
  uint4* o8 = (uint4*)ekv_bf;
  const size_t stride = (size_t)gridDim.x * blockDim.x;
  for (size_t i = (size_t)blockIdx.x * blockDim.x + threadIdx.x; i < total; i += stride) {
    const uint4 e = e8[i], v = v8[i];
    uint4 r;
    r.x = mul2bf(e.x, v.x);
    r.y = mul2bf(e.y, v.y);
    r.z = mul2bf(e.z, v.z);
    r.w = mul2bf(e.w, v.w);
    o8[i] = r;
  }
}

// ---------------------------------------------------------------------------
// Kernel 2: eB = bf16(exp(pos_bias)), N*N elements, vectorized.
// ---------------------------------------------------------------------------
__global__ __launch_bounds__(256) void expb_kernel(
    const float* __restrict__ pb, unsigned short* __restrict__ eb)
{
  const size_t total = (size_t)NN * NN / 4;
  const float4* p4 = (const float4*)pb;
  uint2* o4 = (uint2*)eb;
  const size_t stride = (size_t)gridDim.x * blockDim.x;
  for (size_t i = (size_t)blockIdx.x * blockDim.x + threadIdx.x; i < total; i += stride) {
    float4 v = p4[i];
    union { unsigned short s[4]; uint2 u; } r;
    r.s[0] = f2bf(__expf(v.x));
    r.s[1] = f2bf(__expf(v.y));
    r.s[2] = f2bf(__expf(v.z));
    r.s[3] = f2bf(__expf(v.w));
    o4[i] = r.u;
  }
}

// ---------------------------------------------------------------------------
// Kernel 3: bf16 MFMA GEMM, m97 structure, K-SPLIT x2 in one dispatch.
// blockIdx.z = split s: K-range [s*2048, s*2048+2048).
// Split 0 -> part0 (f32), split 1 -> part1 (bf16; fits 96MiB ws, error ~6e-8).
// Grid 16 x 32 x 2 = 1024 blocks = 4 blocks/CU (was 512 = 2/CU, Occ 21%).
// ---------------------------------------------------------------------------
#define BM 128
#define BN 128
#define BK 32
#define KSPLIT 2048

__global__ __launch_bounds__(256) void gemm_bt(
    const unsigned short* __restrict__ A,
    const unsigned short* __restrict__ Bt,
    float* __restrict__ part0,
    unsigned short* __restrict__ part1,
    const int N, const int K)
{
  __shared__ unsigned short As[BM * BK];
  __shared__ unsigned short Bs[BN * BK];

  const int tid  = threadIdx.x;
  const int m0   = blockIdx.x * BM;
  const int n0   = blockIdx.y * BN;
  const int z    = blockIdx.z;          // K-split index (uniform)
  const int koff = z * KSPLIT;
  const int wid  = tid >> 6, lane = tid & 63;
  const int wr   = wid >> 1, wc = wid & 1;
  const int fr   = lane & 15, kq = lane >> 4;

  f32x4 acc[4][4] = {};

  for (int k0 = koff; k0 < koff + KSPLIT; k0 += BK) {
#pragma unroll
    for (int i = 0; i < 2; ++i) {
      const int s = tid + i * 256;
      const int row = s >> 2, kb = s & 3;
      const unsigned short* g = A + (size_t)(m0 + row) * K + (k0 + kb * 8);
      __builtin_amdgcn_global_load_lds(
          (const __attribute__((address_space(1))) void*)g,
          (__attribute__((address_space(3))) void*)&As[s * 8], 16, 0, 0);
    }
#pragma unroll
    for (int i = 0; i < 2; ++i) {
      const int s = tid + i * 256;
      const int row = s >> 2, kb = s & 3;
      const unsigned short* g = Bt + (size_t)(n0 + row) * K + (k0 + kb * 8);
      __builtin_amdgcn_global_load_lds(
          (const __attribute__((address_space(1))) void*)g,
          (__attribute__((address_space(3))) void*)&Bs[s * 8], 16, 0, 0);
    }
    __syncthreads();

    bf16x8 af[4], bfr[4];
#pragma unroll
    for (int m = 0; m < 4; ++m)
      af[m] = *reinterpret_cast<const bf16x8*>(&As[(wr * 64 + m * 16 + fr) * BK + kq * 8]);
#pragma unroll
    for (int n = 0; n < 4; ++n)
      bfr[n] = *reinterpret_cast<const bf16x8*>(&Bs[(wc * 64 + n * 16 + fr) * BK + kq * 8]);

#pragma unroll
    for (int m = 0; m < 4; ++m)
#pragma unroll
      for (int n = 0; n < 4; ++n)
        acc[m][n] = __builtin_amdgcn_mfma_f32_16x16x32_bf16(af[m], bfr[n], acc[m][n], 0, 0, 0);

    __syncthreads();
  }

  // C/D layout (m89): col = lane&15, row = kq*4 + j
#pragma unroll
  for (int m = 0; m < 4; ++m)
#pragma unroll
    for (int n = 0; n < 4; ++n) {
      const int row0 = m0 + wr * 64 + m * 16 + kq * 4;
      const int col  = n0 + wc * 64 + n * 16 + fr;
      if (z == 0) {
#pragma unroll
        for (int j = 0; j < 4; ++j)
          part0[(size_t)(row0 + j) * N + col] = acc[m][n][j];
      } else {
#pragma unroll
        for (int j = 0; j < 4; ++j)
          part1[(size_t)(row0 + j) * N + col] = f2bf(acc[m][n][j]);
      }
    }
}

// ---------------------------------------------------------------------------
// Kernel 4: out[i] = out[i] * (num0+num1) / (den0+den1), in place on d_out
// (d_out holds sigmoid(q) written by qkv_mfma; fully rewritten every call).
// ---------------------------------------------------------------------------
__global__ __launch_bounds__(256) void epilogue_kernel(
    const float* __restrict__ part0,
    const unsigned short* __restrict__ part1,
    float* __restrict__ out)
{
  const size_t total4 = (size_t)BB * CC * NN / 4;      // f32x4 count of one half
  const f32x4* n0 = (const f32x4*)part0;
  const f32x4* d0 = n0 + total4;
  const uint2* n1 = (const uint2*)part1;               // 4 bf16 per uint2
  const uint2* d1 = n1 + total4;
  f32x4* o4 = (f32x4*)out;
  const size_t stride = (size_t)gridDim.x * blockDim.x;
  for (size_t i = (size_t)blockIdx.x * blockDim.x + threadIdx.x; i < total4; i += stride) {
    const f32x4 a0 = n0[i], b0 = d0[i];
    const uint2 a1 = n1[i], b1 = d1[i];
    const f32x4 sg = o4[i];
    f32x4 r;
    r[0] = sg[0] * (a0[0] + bf2f((unsigned short)(a1.x & 0xffff))) /
                   (b0[0] + bf2f((unsigned short)(b1.x & 0xffff)));
    r[1] = sg[1] * (a0[1] + bf2f((unsigned short)(a1.x >> 16))) /
                   (b0[1] + bf2f((unsigned short)(b1.x >> 16)));
    r[2] = sg[2] * (a0[2] + bf2f((unsigned short)(a1.y & 0xffff))) /
                   (b0[2] + bf2f((unsigned short)(b1.y & 0xffff)));
    r[3] = sg[3] * (a0[3] + bf2f((unsigned short)(a1.y >> 16))) /
                   (b0[3] + bf2f((unsigned short)(b1.y >> 16)));
    o4[i] = r;
  }
}

// ---------------------------------------------------------------------------
// Workspace (96 MiB total, same proven budget as R1/R2):
//   [0, 16MiB)     : Abf  = bf16 [2048][4096]  (rows 0..1023 ekv, 1024..2047 ek)
//   [16MiB, 48MiB) : eBbf = bf16 [4096][4096]
//   [48MiB, 80MiB) : part0 = f32 [2048][4096]  (K-half 0); v_bf bf16[1024][4096]
//                    ALIASES its first 8MiB (read by ekv_kernel before gemm)
//   [80MiB, 96MiB) : part1 = bf16 [2048][4096] (K-half 1)
//   sigmoid(q) lives in d_out (written by qkv, updated in place by epilogue).
// ---------------------------------------------------------------------------
extern "C" void kernel_launch(void* const* d_in, const int* in_sizes, int n_in,
                              void* d_out, int out_size, void* d_ws, size_t ws_size,
                              hipStream_t stream) {
  const float* x  = (const float*)d_in[0];
  const float* Wq = (const float*)d_in[1];
  const float* bq = (const float*)d_in[2];
  const float* Wk = (const float*)d_in[3];
  const float* bk = (const float*)d_in[4];
  const float* Wv = (const float*)d_in[5];
  const float* bv = (const float*)d_in[6];
  const float* pb = (const float*)d_in[7];
  float* out = (float*)d_out;

  char* ws = (char*)d_ws;
  unsigned short* Abf   = (unsigned short*)ws;
  unsigned short* eBbf  = (unsigned short*)(ws + (size_t)16777216);
  float*          part0 = (float*)(ws + (size_t)16777216 + 33554432);
  unsigned short* part1 = (unsigned short*)(ws + (size_t)16777216 + 33554432 + 33554432);

  unsigned short* ekv_bf = Abf;                       // rows 0..1023  -> numerator
  unsigned short* ek_bf  = Abf + (size_t)1024 * NN;   // rows 1024..2047 -> denominator
  unsigned short* v_bf   = (unsigned short*)part0;    // aliases part0 head (read before gemm)

  hipLaunchKernelGGL(qkv_mfma, dim3(NN / 128, 3, BB), dim3(256), 0, stream,
                     x, Wq, bq, Wk, bk, Wv, bv, out, ek_bf, v_bf);
  hipLaunchKernelGGL(ekv_kernel, dim3(1024), dim3(256), 0, stream,
                     ek_bf, v_bf, ekv_bf);
  hipLaunchKernelGGL(expb_kernel, dim3(2048), dim3(256), 0, stream, pb, eBbf);
  hipLaunchKernelGGL(gemm_bt, dim3(2048 / BM, NN / BN, 2), dim3(256), 0, stream,
                     Abf, eBbf, part0, part1, NN, NN);
  hipLaunchKernelGGL(epilogue_kernel, dim3(2048), dim3(256), 0, stream,
                     part0, part1, out);
}

// Round 4
// 123.294 us; speedup vs baseline: 2.1124x; 1.3403x over previous
//
#include <hip/hip_runtime.h>
#include <hip/hip_bf16.h>

// Problem constants (AFT_FULL): x (B=8, C=128, H*W*D = N=4096)
#define BB 8
#define CC 128
#define NN 4096

typedef __bf16 bf16x8 __attribute__((ext_vector_type(8)));
typedef float f32x4 __attribute__((ext_vector_type(4)));
typedef unsigned short ushort_t;

static __device__ __forceinline__ unsigned short f2bf(float f) {
  __hip_bfloat16 h = __float2bfloat16(f);
  return __builtin_bit_cast(unsigned short, h);
}
static __device__ __forceinline__ float bf2f(unsigned short u) {
  return __builtin_bit_cast(float, (unsigned int)u << 16);
}

// ---------------------------------------------------------------------------
// Kernel 1: QKV via MFMA (unchanged from R2/R3, passed).
// ---------------------------------------------------------------------------
__global__ __launch_bounds__(256) void qkv_mfma(
    const float* __restrict__ x,
    const float* __restrict__ Wq, const float* __restrict__ bq,
    const float* __restrict__ Wk, const float* __restrict__ bk,
    const float* __restrict__ Wv, const float* __restrict__ bv,
    float* __restrict__ sq,
    unsigned short* __restrict__ ek_bf,
    unsigned short* __restrict__ v_bf)
{
  __shared__ __align__(16) unsigned short XT[128 * 128];
  __shared__ __align__(16) unsigned short WT[128 * 128];

  const int tid = threadIdx.x;
  const int n0  = blockIdx.x * 128;
  const int g   = blockIdx.y;
  const int b   = blockIdx.z;

  const float* W    = (g == 0) ? Wq : (g == 1) ? Wk : Wv;
  const float* bias = (g == 0) ? bq : (g == 1) ? bk : bv;

  {
    const int c   = tid & 127;
    const int grp = tid >> 7;
    const float* xrow = x + ((size_t)(b * CC + c)) * NN + n0;
#pragma unroll
    for (int i = 0; i < 16; ++i) {
      const int n4 = grp * 16 + i;
      const float4 v4 = *(const float4*)(xrow + n4 * 4);
      const float vv[4] = {v4.x, v4.y, v4.z, v4.w};
#pragma unroll
      for (int j = 0; j < 4; ++j) {
        const int n = n4 * 4 + j;
        const int byte = (2 * (n * 128 + c)) ^ ((n & 7) << 4);
        *(unsigned short*)((char*)XT + byte) = f2bf(vv[j]);
      }
    }
  }
  {
    const int c   = tid & 127;
    const int grp = tid >> 7;
#pragma unroll
    for (int i = 0; i < 64; ++i) {
      const int co = grp * 64 + i;
      const float wv = W[(size_t)co * CC + c];
      const int byte = (2 * (co * 128 + c)) ^ ((co & 7) << 4);
      *(unsigned short*)((char*)WT + byte) = f2bf(wv);
    }
  }
  __syncthreads();

  const int lane = tid & 63, wid = tid >> 6;
  const int wr = wid >> 1, wc = wid & 1;
  const int fr = lane & 15, kq = lane >> 4;

  f32x4 acc[4][4] = {};
#pragma unroll
  for (int k0 = 0; k0 < 128; k0 += 32) {
    bf16x8 af[4], bfr[4];
#pragma unroll
    for (int m = 0; m < 4; ++m) {
      const int r = wr * 64 + m * 16 + fr;
      const int byte = (2 * (r * 128 + k0 + kq * 8)) ^ ((r & 7) << 4);
      af[m] = *(const bf16x8*)((const char*)WT + byte);
    }
#pragma unroll
    for (int n = 0; n < 4; ++n) {
      const int r = wc * 64 + n * 16 + fr;
      const int byte = (2 * (r * 128 + k0 + kq * 8)) ^ ((r & 7) << 4);
      bfr[n] = *(const bf16x8*)((const char*)XT + byte);
    }
#pragma unroll
    for (int m = 0; m < 4; ++m)
#pragma unroll
      for (int n = 0; n < 4; ++n)
        acc[m][n] = __builtin_amdgcn_mfma_f32_16x16x32_bf16(af[m], bfr[n], acc[m][n], 0, 0, 0);
  }

#pragma unroll
  for (int m = 0; m < 4; ++m)
#pragma unroll
    for (int n = 0; n < 4; ++n) {
      const int row0 = wr * 64 + m * 16 + kq * 4;
      const int col  = n0 + wc * 64 + n * 16 + fr;
#pragma unroll
      for (int j = 0; j < 4; ++j) {
        const int co = row0 + j;
        const float val = acc[m][n][j] + bias[co];
        const size_t o = ((size_t)(b * CC + co)) * NN + col;
        if (g == 0)      sq[o]    = 1.0f / (1.0f + __expf(-val));
        else if (g == 1) ek_bf[o] = f2bf(__expf(val));
        else             v_bf[o]  = f2bf(val);
      }
    }
}

// ---------------------------------------------------------------------------
// Kernel 1b: ekv = ek * v (unchanged)
// ---------------------------------------------------------------------------
static __device__ __forceinline__ unsigned int mul2bf(unsigned int a, unsigned int b) {
  const float alo = __builtin_bit_cast(float, a << 16);
  const float ahi = __builtin_bit_cast(float, a & 0xffff0000u);
  const float blo = __builtin_bit_cast(float, b << 16);
  const float bhi = __builtin_bit_cast(float, b & 0xffff0000u);
  return (unsigned int)f2bf(alo * blo) | ((unsigned int)f2bf(ahi * bhi) << 16);
}

__global__ __launch_bounds__(256) void ekv_kernel(
    const unsigned short* __restrict__ ek_bf,
    const unsigned short* __restrict__ v_bf,
    unsigned short* __restrict__ ekv_bf)
{
  const size_t total = (size_t)BB * CC * NN / 8;
  const uint4* e8 = (const uint4*)ek_bf;
  const uint4* v8 = (const uint4*)v_bf;
  uint4* o8 = (uint4*)ekv_bf;
  const size_t stride = (size_t)gridDim.x * blockDim.x;
  for (size_t i = (size_t)blockIdx.x * blockDim.x + threadIdx.x; i < total; i += stride) {
    const uint4 e = e8[i], v = v8[i];
    uint4 r;
    r.x = mul2bf(e.x, v.x);
    r.y = mul2bf(e.y, v.y);
    r.z = mul2bf(e.z, v.z);
    r.w = mul2bf(e.w, v.w);
    o8[i] = r;
  }
}

// ---------------------------------------------------------------------------
// Kernel 2: eB = bf16(exp(pos_bias)) (unchanged)
// ---------------------------------------------------------------------------
__global__ __launch_bounds__(256) void expb_kernel(
    const float* __restrict__ pb, unsigned short* __restrict__ eb)
{
  const size_t total = (size_t)NN * NN / 4;
  const float4* p4 = (const float4*)pb;
  uint2* o4 = (uint2*)eb;
  const size_t stride = (size_t)gridDim.x * blockDim.x;
  for (size_t i = (size_t)blockIdx.x * blockDim.x + threadIdx.x; i < total; i += stride) {
    float4 v = p4[i];
    union { unsigned short s[4]; uint2 u; } r;
    r.s[0] = f2bf(__expf(v.x));
    r.s[1] = f2bf(__expf(v.y));
    r.s[2] = f2bf(__expf(v.z));
    r.s[3] = f2bf(__expf(v.w));
    o4[i] = r.u;
  }
}

// ---------------------------------------------------------------------------
// Kernel 3: 256x256 8-phase counted-vmcnt bf16 MFMA GEMM (T1+T2+T3+T4+T5).
// A: 2048x4096 bf16 rows=[ekv;ek]; Bt: 4096x4096 bf16 (eB); K-split x2 (bz).
// 512 thr = 8 waves (2M x 4N), wave output 128x64. BK=64, 2 K-tiles/iter.
// LDS 128KiB: A slots (d,h) at (d*2+h)*16384; B slots at 65536+(d*2+h)*16384.
// Swizzle byte^=((r&7)<<4); gload_lds = linear dest + inverse-swizzled source.
// Schedule per iter: phases 1-4 compute dbuf0 (Q(mq,nq) of tile 2i), 5-8 dbuf1.
// Stages: p1:A1h1 p2:B1h0 p3:B1h1 (tile 2i+1) | p4:A0h0' p5:A0h1' p6:B0h0'
// p7:B0h1' (tile 2i+2) | p8:A1h0' (tile 2i+3).  vmcnt(2) at p4 & p8
// (last iter: vmcnt(0) at p4).  Raw s_barrier only — no vmcnt(0) drains.
// ---------------------------------------------------------------------------
#define NIT 16   // iterations per block: 16 * 2 K-tiles * 64 = 2048 = K/2

__global__ __launch_bounds__(512, 2) void gemm8p(
    const unsigned short* __restrict__ A,
    const unsigned short* __restrict__ Bt,
    float* __restrict__ part0,
    unsigned short* __restrict__ part1,
    const int N, const int K)
{
  __shared__ __align__(16) unsigned short L[65536];   // 128 KiB

  const int tid = threadIdx.x;

  // Bijective XCD swizzle: each XCD gets all 8 m-tiles x 2 n-tiles x 2 z.
  const int lin = blockIdx.x + 8 * blockIdx.y + 128 * blockIdx.z;  // 0..255
  const int xcd = lin & 7, rr = lin >> 3;
  const int bx = rr & 7;
  const int by = 2 * xcd + ((rr >> 3) & 1);
  const int bz = rr >> 4;
  const int m0 = bx * 256, n0 = by * 256, koff = bz * 2048;

  const int wid = tid >> 6, lane = tid & 63;
  const int wr = wid >> 2, wc = wid & 3;       // 2M x 4N waves
  const int fr = lane & 15, kq = lane >> 4;

  // ---- staging: 2 x gload_lds(16B) per thread per half-tile slot
#define ABASE(d, h) (((d) * 2 + (h)) * 16384)
#define BBASE(d, h) (65536 + ((d) * 2 + (h)) * 16384)
#define STAGE(P, growbase, kt, ldsbase)                                        \
  {                                                                            \
    const int gk = koff + (kt) * 64;                                           \
    _Pragma("unroll")                                                          \
    for (int i_ = 0; i_ < 2; ++i_) {                                           \
      const int s_ = i_ * 8192 + tid * 16;                                     \
      const int r_ = s_ >> 7;                                                  \
      const int l_ = s_ ^ ((r_ & 7) << 4);                                     \
      const unsigned short* src_ =                                             \
          (P) + (size_t)((growbase) + r_) * K + gk + ((l_ & 127) >> 1);        \
      __builtin_amdgcn_global_load_lds(                                        \
          (const __attribute__((address_space(1))) void*)src_,                 \
          (__attribute__((address_space(3))) void*)&L[((ldsbase) + s_) >> 1],  \
          16, 0, 0);                                                           \
    }                                                                          \
  }

  // ---- swizzled fragment reads
#define LDA_F(dst, d, m, ks)                                                   \
  {                                                                            \
    const int r_ = (m) * 16 + fr;                                              \
    const int byte_ = ABASE(d, wr) +                                           \
        ((r_ * 128 + (ks) * 64 + kq * 16) ^ ((r_ & 7) << 4));                  \
    dst = *(const bf16x8*)((const char*)L + byte_);                            \
  }
#define LDB_F(dst, d, n, ks)                                                   \
  {                                                                            \
    const int r_ = (wc & 1) * 64 + (n) * 16 + fr;                              \
    const int byte_ = BBASE(d, (wc >> 1)) +                                    \
        ((r_ * 128 + (ks) * 64 + kq * 16) ^ ((r_ & 7) << 4));                  \
    dst = *(const bf16x8*)((const char*)L + byte_);                            \
  }

  f32x4 acc[8][4] = {};
  bf16x8 a[4][2], b[2][2];

#define MFMA16(mq, nq)                                                         \
  __builtin_amdgcn_s_setprio(1);                                               \
  _Pragma("unroll")                                                            \
  for (int m_ = 0; m_ < 4; ++m_)                                               \
    _Pragma("unroll")                                                          \
    for (int n_ = 0; n_ < 2; ++n_)                                             \
      _Pragma("unroll")                                                        \
      for (int ks_ = 0; ks_ < 2; ++ks_)                                        \
        acc[(mq) * 4 + m_][(nq) * 2 + n_] =                                    \
            __builtin_amdgcn_mfma_f32_16x16x32_bf16(                           \
                a[m_][ks_], b[n_][ks_], acc[(mq) * 4 + m_][(nq) * 2 + n_],     \
                0, 0, 0);                                                      \
  __builtin_amdgcn_s_setprio(0);

#define READ_A(d, mq)                                                          \
  _Pragma("unroll")                                                            \
  for (int m_ = 0; m_ < 4; ++m_)                                               \
    _Pragma("unroll")                                                          \
    for (int ks_ = 0; ks_ < 2; ++ks_) LDA_F(a[m_][ks_], d, (mq) * 4 + m_, ks_)
#define READ_B(d, nq)                                                          \
  _Pragma("unroll")                                                            \
  for (int n_ = 0; n_ < 2; ++n_)                                               \
    _Pragma("unroll")                                                          \
    for (int ks_ = 0; ks_ < 2; ++ks_) LDB_F(b[n_][ks_], d, (nq) * 2 + n_, ks_)

#define VMCNT2 asm volatile("s_waitcnt vmcnt(2)" ::: "memory");
#define VMCNT0 asm volatile("s_waitcnt vmcnt(0)" ::: "memory");
#define PHASE_END                                                              \
  __builtin_amdgcn_s_barrier();                                                \
  __builtin_amdgcn_sched_barrier(0);

  // ---- prologue: stage A0h0,A0h1,B0h0,B0h1 (tile 0) + A1h0 (tile 1)
  STAGE(A, m0, 0, ABASE(0, 0));
  STAGE(A, m0 + 128, 0, ABASE(0, 1));
  STAGE(Bt, n0, 0, BBASE(0, 0));
  STAGE(Bt, n0 + 128, 0, BBASE(0, 1));
  STAGE(A, m0, 1, ABASE(1, 0));
  VMCNT2           // first 4 slots landed
  PHASE_END

  for (int it = 0; it < NIT; ++it) {
    const bool more = (it + 1 < NIT);
    const int kt1 = 2 * it + 1;

    // ---- phase 1: Q(0,0) x dbuf0 ; stage A1h1 (tile kt1)
    READ_A(0, 0) READ_B(0, 0)
    STAGE(A, m0 + 128, kt1, ABASE(1, 1));
    MFMA16(0, 0)
    PHASE_END

    // ---- phase 2: Q(0,1) x dbuf0 ; stage B1h0
    READ_B(0, 1)
    STAGE(Bt, n0, kt1, BBASE(1, 0));
    MFMA16(0, 1)
    PHASE_END

    // ---- phase 3: Q(1,0) x dbuf0 ; stage B1h1
    READ_A(0, 1) READ_B(0, 0)
    STAGE(Bt, n0 + 128, kt1, BBASE(1, 1));
    MFMA16(1, 0)
    PHASE_END

    // ---- phase 4: Q(1,1) x dbuf0 ; stage A0h0' ; WAIT d1
    READ_B(0, 1)
    if (more) STAGE(A, m0, kt1 + 1, ABASE(0, 0));
    MFMA16(1, 1)
    if (more) { VMCNT2 } else { VMCNT0 }
    PHASE_END

    // ---- phase 5: Q(0,0) x dbuf1 ; stage A0h1'
    READ_A(1, 0) READ_B(1, 0)
    if (more) STAGE(A, m0 + 128, kt1 + 1, ABASE(0, 1));
    MFMA16(0, 0)
    PHASE_END

    // ---- phase 6: Q(0,1) x dbuf1 ; stage B0h0'
    READ_B(1, 1)
    if (more) STAGE(Bt, n0, kt1 + 1, BBASE(0, 0));
    MFMA16(0, 1)
    PHASE_END

    // ---- phase 7: Q(1,0) x dbuf1 ; stage B0h1'
    READ_A(1, 1) READ_B(1, 0)
    if (more) STAGE(Bt, n0 + 128, kt1 + 1, BBASE(0, 1));
    MFMA16(1, 0)
    PHASE_END

    // ---- phase 8: Q(1,1) x dbuf1 ; stage A1h0'' ; WAIT next d0
    READ_B(1, 1)
    if (more) STAGE(A, m0, kt1 + 2, ABASE(1, 0));
    MFMA16(1, 1)
    VMCNT2
    PHASE_END
  }

  // ---- C write: row0 = m0 + wr*128 + m*16 + kq*4, col = n0 + wc*64 + n*16 + fr
#pragma unroll
  for (int m = 0; m < 8; ++m)
#pragma unroll
    for (int n = 0; n < 4; ++n) {
      const int row0 = m0 + wr * 128 + m * 16 + kq * 4;
      const int col  = n0 + wc * 64 + n * 16 + fr;
      if (bz == 0) {
#pragma unroll
        for (int j = 0; j < 4; ++j)
          part0[(size_t)(row0 + j) * N + col] = acc[m][n][j];
      } else {
#pragma unroll
        for (int j = 0; j < 4; ++j)
          part1[(size_t)(row0 + j) * N + col] = f2bf(acc[m][n][j]);
      }
    }
}

// ---------------------------------------------------------------------------
// Kernel 4: out[i] = out[i] * (num0+num1) / (den0+den1)  (unchanged R3)
// ---------------------------------------------------------------------------
__global__ __launch_bounds__(256) void epilogue_kernel(
    const float* __restrict__ part0,
    const unsigned short* __restrict__ part1,
    float* __restrict__ out)
{
  const size_t total4 = (size_t)BB * CC * NN / 4;
  const f32x4* n0 = (const f32x4*)part0;
  const f32x4* d0 = n0 + total4;
  const uint2* n1 = (const uint2*)part1;
  const uint2* d1 = n1 + total4;
  f32x4* o4 = (f32x4*)out;
  const size_t stride = (size_t)gridDim.x * blockDim.x;
  for (size_t i = (size_t)blockIdx.x * blockDim.x + threadIdx.x; i < total4; i += stride) {
    const f32x4 a0 = n0[i], b0 = d0[i];
    const uint2 a1 = n1[i], b1 = d1[i];
    const f32x4 sg = o4[i];
    f32x4 r;
    r[0] = sg[0] * (a0[0] + bf2f((unsigned short)(a1.x & 0xffff))) /
                   (b0[0] + bf2f((unsigned short)(b1.x & 0xffff)));
    r[1] = sg[1] * (a0[1] + bf2f((unsigned short)(a1.x >> 16))) /
                   (b0[1] + bf2f((unsigned short)(b1.x >> 16)));
    r[2] = sg[2] * (a0[2] + bf2f((unsigned short)(a1.y & 0xffff))) /
                   (b0[2] + bf2f((unsigned short)(b1.y & 0xffff)));
    r[3] = sg[3] * (a0[3] + bf2f((unsigned short)(a1.y >> 16))) /
                   (b0[3] + bf2f((unsigned short)(b1.y >> 16)));
    o4[i] = r;
  }
}

// ---------------------------------------------------------------------------
// Workspace (96 MiB, same proven budget):
//   [0, 16MiB)     : Abf  = bf16 [2048][4096]  (rows 0..1023 ekv, 1024..2047 ek)
//   [16MiB, 48MiB) : eBbf = bf16 [4096][4096]
//   [48MiB, 80MiB) : part0 = f32 [2048][4096] (z=0); v_bf aliases first 8MiB
//   [80MiB, 96MiB) : part1 = bf16 [2048][4096] (z=1)
//   sigmoid(q) lives in d_out (written by qkv, updated in place by epilogue).
// ---------------------------------------------------------------------------
extern "C" void kernel_launch(void* const* d_in, const int* in_sizes, int n_in,
                              void* d_out, int out_size, void* d_ws, size_t ws_size,
                              hipStream_t stream) {
  const float* x  = (const float*)d_in[0];
  const float* Wq = (const float*)d_in[1];
  const float* bq = (const float*)d_in[2];
  const float* Wk = (const float*)d_in[3];
  const float* bk = (const float*)d_in[4];
  const float* Wv = (const float*)d_in[5];
  const float* bv = (const float*)d_in[6];
  const float* pb = (const float*)d_in[7];
  float* out = (float*)d_out;

  char* ws = (char*)d_ws;
  unsigned short* Abf   = (unsigned short*)ws;
  unsigned short* eBbf  = (unsigned short*)(ws + (size_t)16777216);
  float*          part0 = (float*)(ws + (size_t)16777216 + 33554432);
  unsigned short* part1 = (unsigned short*)(ws + (size_t)16777216 + 33554432 + 33554432);

  unsigned short* ekv_bf = Abf;
  unsigned short* ek_bf  = Abf + (size_t)1024 * NN;
  unsigned short* v_bf   = (unsigned short*)part0;   // aliases part0 head (read before gemm)

  hipLaunchKernelGGL(qkv_mfma, dim3(NN / 128, 3, BB), dim3(256), 0, stream,
                     x, Wq, bq, Wk, bk, Wv, bv, out, ek_bf, v_bf);
  hipLaunchKernelGGL(ekv_kernel, dim3(1024), dim3(256), 0, stream,
                     ek_bf, v_bf, ekv_bf);
  hipLaunchKernelGGL(expb_kernel, dim3(2048), dim3(256), 0, stream, pb, eBbf);
  hipLaunchKernelGGL(gemm8p, dim3(8, 16, 2), dim3(512), 0, stream,
                     Abf, eBbf, part0, part1, NN, NN);
  hipLaunchKernelGGL(epilogue_kernel, dim3(2048), dim3(256), 0, stream,
                     part0, part1, out);
}

// Round 5
// 121.050 us; speedup vs baseline: 2.1516x; 1.0185x over previous
//
#include <hip/hip_runtime.h>
#include <hip/hip_bf16.h>

// Problem constants (AFT_FULL): x (B=8, C=128, H*W*D = N=4096)
#define BB 8
#define CC 128
#define NN 4096

typedef __bf16 bf16x8 __attribute__((ext_vector_type(8)));
typedef float f32x4 __attribute__((ext_vector_type(4)));

static __device__ __forceinline__ unsigned short f2bf(float f) {
  __hip_bfloat16 h = __float2bfloat16(f);
  return __builtin_bit_cast(unsigned short, h);
}
static __device__ __forceinline__ float bf2f(unsigned short u) {
  return __builtin_bit_cast(float, (unsigned int)u << 16);
}

// ---------------------------------------------------------------------------
// Kernel 1: QKV via MFMA (unchanged from R2-R4, passed).
// ---------------------------------------------------------------------------
__global__ __launch_bounds__(256) void qkv_mfma(
    const float* __restrict__ x,
    const float* __restrict__ Wq, const float* __restrict__ bq,
    const float* __restrict__ Wk, const float* __restrict__ bk,
    const float* __restrict__ Wv, const float* __restrict__ bv,
    float* __restrict__ sq,
    unsigned short* __restrict__ ek_bf,
    unsigned short* __restrict__ v_bf)
{
  __shared__ __align__(16) unsigned short XT[128 * 128];
  __shared__ __align__(16) unsigned short WT[128 * 128];

  const int tid = threadIdx.x;
  const int n0  = blockIdx.x * 128;
  const int g   = blockIdx.y;
  const int b   = blockIdx.z;

  const float* W    = (g == 0) ? Wq : (g == 1) ? Wk : Wv;
  const float* bias = (g == 0) ? bq : (g == 1) ? bk : bv;

  {
    const int c   = tid & 127;
    const int grp = tid >> 7;
    const float* xrow = x + ((size_t)(b * CC + c)) * NN + n0;
#pragma unroll
    for (int i = 0; i < 16; ++i) {
      const int n4 = grp * 16 + i;
      const float4 v4 = *(const float4*)(xrow + n4 * 4);
      const float vv[4] = {v4.x, v4.y, v4.z, v4.w};
#pragma unroll
      for (int j = 0; j < 4; ++j) {
        const int n = n4 * 4 + j;
        const int byte = (2 * (n * 128 + c)) ^ ((n & 7) << 4);
        *(unsigned short*)((char*)XT + byte) = f2bf(vv[j]);
      }
    }
  }
  {
    const int c   = tid & 127;
    const int grp = tid >> 7;
#pragma unroll
    for (int i = 0; i < 64; ++i) {
      const int co = grp * 64 + i;
      const float wv = W[(size_t)co * CC + c];
      const int byte = (2 * (co * 128 + c)) ^ ((co & 7) << 4);
      *(unsigned short*)((char*)WT + byte) = f2bf(wv);
    }
  }
  __syncthreads();

  const int lane = tid & 63, wid = tid >> 6;
  const int wr = wid >> 1, wc = wid & 1;
  const int fr = lane & 15, kq = lane >> 4;

  f32x4 acc[4][4] = {};
#pragma unroll
  for (int k0 = 0; k0 < 128; k0 += 32) {
    bf16x8 af[4], bfr[4];
#pragma unroll
    for (int m = 0; m < 4; ++m) {
      const int r = wr * 64 + m * 16 + fr;
      const int byte = (2 * (r * 128 + k0 + kq * 8)) ^ ((r & 7) << 4);
      af[m] = *(const bf16x8*)((const char*)WT + byte);
    }
#pragma unroll
    for (int n = 0; n < 4; ++n) {
      const int r = wc * 64 + n * 16 + fr;
      const int byte = (2 * (r * 128 + k0 + kq * 8)) ^ ((r & 7) << 4);
      bfr[n] = *(const bf16x8*)((const char*)XT + byte);
    }
#pragma unroll
    for (int m = 0; m < 4; ++m)
#pragma unroll
      for (int n = 0; n < 4; ++n)
        acc[m][n] = __builtin_amdgcn_mfma_f32_16x16x32_bf16(af[m], bfr[n], acc[m][n], 0, 0, 0);
  }

#pragma unroll
  for (int m = 0; m < 4; ++m)
#pragma unroll
    for (int n = 0; n < 4; ++n) {
      const int row0 = wr * 64 + m * 16 + kq * 4;
      const int col  = n0 + wc * 64 + n * 16 + fr;
#pragma unroll
      for (int j = 0; j < 4; ++j) {
        const int co = row0 + j;
        const float val = acc[m][n][j] + bias[co];
        const size_t o = ((size_t)(b * CC + co)) * NN + col;
        if (g == 0)      sq[o]    = 1.0f / (1.0f + __expf(-val));
        else if (g == 1) ek_bf[o] = f2bf(__expf(val));
        else             v_bf[o]  = f2bf(val);
      }
    }
}

// ---------------------------------------------------------------------------
// Kernel 1b: ekv = ek * v (unchanged)
// ---------------------------------------------------------------------------
static __device__ __forceinline__ unsigned int mul2bf(unsigned int a, unsigned int b) {
  const float alo = __builtin_bit_cast(float, a << 16);
  const float ahi = __builtin_bit_cast(float, a & 0xffff0000u);
  const float blo = __builtin_bit_cast(float, b << 16);
  const float bhi = __builtin_bit_cast(float, b & 0xffff0000u);
  return (unsigned int)f2bf(alo * blo) | ((unsigned int)f2bf(ahi * bhi) << 16);
}

__global__ __launch_bounds__(256) void ekv_kernel(
    const unsigned short* __restrict__ ek_bf,
    const unsigned short* __restrict__ v_bf,
    unsigned short* __restrict__ ekv_bf)
{
  const size_t total = (size_t)BB * CC * NN / 8;
  const uint4* e8 = (const uint4*)ek_bf;
  const uint4* v8 = (const uint4*)v_bf;
  uint4* o8 = (uint4*)ekv_bf;
  const size_t stride = (size_t)gridDim.x * blockDim.x;
  for (size_t i = (size_t)blockIdx.x * blockDim.x + threadIdx.x; i < total; i += stride) {
    const uint4 e = e8[i], v = v8[i];
    uint4 r;
    r.x = mul2bf(e.x, v.x);
    r.y = mul2bf(e.y, v.y);
    r.z = mul2bf(e.z, v.z);
    r.w = mul2bf(e.w, v.w);
    o8[i] = r;
  }
}

// ---------------------------------------------------------------------------
// Kernel 2: eB = bf16(exp(pos_bias)) (unchanged)
// ---------------------------------------------------------------------------
__global__ __launch_bounds__(256) void expb_kernel(
    const float* __restrict__ pb, unsigned short* __restrict__ eb)
{
  const size_t total = (size_t)NN * NN / 4;
  const float4* p4 = (const float4*)pb;
  uint2* o4 = (uint2*)eb;
  const size_t stride = (size_t)gridDim.x * blockDim.x;
  for (size_t i = (size_t)blockIdx.x * blockDim.x + threadIdx.x; i < total; i += stride) {
    float4 v = p4[i];
    union { unsigned short s[4]; uint2 u; } r;
    r.s[0] = f2bf(__expf(v.x));
    r.s[1] = f2bf(__expf(v.y));
    r.s[2] = f2bf(__expf(v.z));
    r.s[3] = f2bf(__expf(v.w));
    o4[i] = r.u;
  }
}

// ---------------------------------------------------------------------------
// Kernel 3: 256x256 quadrant-phase deep-pipeline bf16 MFMA GEMM.
// Per K-tile (BK=64): 4 phases = C-quadrants (ha,hb). Waves 2x4 over 64x32
// sub-tiles WITHIN the quadrant -> each phase reads only A-half ha / B-half hb.
// Slots free at staggered phases -> stages for tile d+2 at p2/p3/p4 give every
// load ~6 phases of latency cover. Counted vmcnt pre-barrier (waits derived by
// issue-order simulation; tails peeled exactly). LDS 128KiB, 2 dbuf.
// ---------------------------------------------------------------------------
#define NT 32   // K-tiles per block: 32 * 64 = 2048 = K/2

__global__ __launch_bounds__(512, 2) void gemm8p(
    const unsigned short* __restrict__ A,
    const unsigned short* __restrict__ Bt,
    float* __restrict__ part0,
    unsigned short* __restrict__ part1,
    const int N, const int K)
{
  __shared__ __align__(16) unsigned short L[65536];   // 128 KiB

  const int tid = threadIdx.x;

  // Bijective XCD swizzle (256 blocks): xcd = lin&7 matches HW round-robin.
  const int lin = blockIdx.x + 8 * blockIdx.y + 128 * blockIdx.z;  // 0..255
  const int xcd = lin & 7, rr = lin >> 3;
  const int bx = rr & 7;
  const int by = 2 * xcd + ((rr >> 3) & 1);
  const int bz = rr >> 4;
  const int m0 = bx * 256, n0 = by * 256, koff = bz * 2048;

  const int lane = tid & 63, wid = tid >> 6;
  const int wr2 = wid >> 2, wc4 = wid & 3;     // 2M x 4N waves, 64x32 subtile
  const int fr = lane & 15, kq = lane >> 4;

#define ABASE(u, h) (((u) * 2 + (h)) * 16384)
#define BBASE(u, h) (65536 + ((u) * 2 + (h)) * 16384)
#define STAGE(P, growbase, kt, ldsbase)                                        \
  {                                                                            \
    const int gk = koff + (kt) * 64;                                           \
    _Pragma("unroll")                                                          \
    for (int i_ = 0; i_ < 2; ++i_) {                                           \
      const int s_ = i_ * 8192 + tid * 16;                                     \
      const int r_ = s_ >> 7;                                                  \
      const int l_ = s_ ^ ((r_ & 7) << 4);                                     \
      const unsigned short* src_ =                                             \
          (P) + (size_t)((growbase) + r_) * K + gk + ((l_ & 127) >> 1);        \
      __builtin_amdgcn_global_load_lds(                                        \
          (const __attribute__((address_space(1))) void*)src_,                 \
          (__attribute__((address_space(3))) void*)&L[((ldsbase) + s_) >> 1],  \
          16, 0, 0);                                                           \
    }                                                                          \
  }

  // Fragment reads (within-half row r, swizzle byte ^= (r&7)<<4)
#define LDF(dst, base, r)                                                      \
  {                                                                            \
    const int byte_ = (base) +                                                 \
        (((r) * 128 + ks_ * 64 + kq * 16) ^ (((r) & 7) << 4));                 \
    dst = *(const bf16x8*)((const char*)L + byte_);                            \
  }

  f32x4 acc[8][4] = {};
  bf16x8 a[4][2], bA[2][2], bB[2][2];

#define READ_A(u, ha)                                                          \
  _Pragma("unroll")                                                            \
  for (int m_ = 0; m_ < 4; ++m_)                                               \
    _Pragma("unroll")                                                          \
    for (int ks_ = 0; ks_ < 2; ++ks_)                                          \
      LDF(a[m_][ks_], ABASE(u, ha), wr2 * 64 + m_ * 16 + fr)
#define READ_B(dst, u, hb)                                                     \
  _Pragma("unroll")                                                            \
  for (int n_ = 0; n_ < 2; ++n_)                                               \
    _Pragma("unroll")                                                          \
    for (int ks_ = 0; ks_ < 2; ++ks_)                                          \
      LDF(dst[n_][ks_], BBASE(u, hb), wc4 * 32 + n_ * 16 + fr)

#define MFMA16(ha, hb, bsrc)                                                   \
  __builtin_amdgcn_s_setprio(1);                                               \
  _Pragma("unroll")                                                            \
  for (int m_ = 0; m_ < 4; ++m_)                                               \
    _Pragma("unroll")                                                          \
    for (int n_ = 0; n_ < 2; ++n_)                                             \
      _Pragma("unroll")                                                        \
      for (int ks_ = 0; ks_ < 2; ++ks_)                                        \
        acc[(ha) * 4 + m_][(hb) * 2 + n_] =                                    \
            __builtin_amdgcn_mfma_f32_16x16x32_bf16(                           \
                a[m_][ks_], bsrc[n_][ks_], acc[(ha) * 4 + m_][(hb) * 2 + n_],  \
                0, 0, 0);                                                      \
  __builtin_amdgcn_s_setprio(0);

#define WAITV_I(n) asm volatile("s_waitcnt vmcnt(" #n ")" ::: "memory")
#define WAITV(n) WAITV_I(n)
#define PHASE_END                                                              \
  __builtin_amdgcn_s_barrier();                                                \
  __builtin_amdgcn_sched_barrier(0);

  // Tile body. Stages (DS=1) target tile dd+2. Waits (pre-barrier, derived):
  //   p1-end: W2 protects Bh1(dd); p2-end: W3 protects Ah1(dd);
  //   p4-end: W1 protects Ah0(dd+1)+Bh0(dd+1).
#define TILE_BODY(dd, DS, W2N, W3N, W1N)                                       \
  {                                                                            \
    const int u_ = (dd) & 1;                                                   \
    /* p1: Q(0,0) */                                                           \
    READ_A(u_, 0); READ_B(bA, u_, 0);                                          \
    MFMA16(0, 0, bA)                                                           \
    WAITV(W2N); PHASE_END                                                      \
    /* p2: Q(0,1) ; stage Ah0(dd+2), Bh0(dd+2) */                              \
    READ_B(bB, u_, 1);                                                         \
    if (DS) { STAGE(A, m0, (dd) + 2, ABASE(u_, 0));                            \
              STAGE(Bt, n0, (dd) + 2, BBASE(u_, 0)); }                         \
    MFMA16(0, 1, bB)                                                           \
    WAITV(W3N); PHASE_END                                                      \
    /* p3: Q(1,0) ; stage Bh1(dd+2) */                                         \
    READ_A(u_, 1);                                                             \
    if (DS) STAGE(Bt, n0 + 128, (dd) + 2, BBASE(u_, 1));                       \
    MFMA16(1, 0, bA)                                                           \
    PHASE_END                                                                  \
    /* p4: Q(1,1) ; stage Ah1(dd+2) */                                         \
    if (DS) STAGE(A, m0 + 128, (dd) + 2, ABASE(u_, 1));                        \
    MFMA16(1, 1, bB)                                                           \
    WAITV(W1N); PHASE_END                                                      \
  }

  // ---- prologue: tiles 0 and 1, per-tile slot order (matches steady counts)
  STAGE(A, m0, 0, ABASE(0, 0));
  STAGE(Bt, n0, 0, BBASE(0, 0));
  STAGE(Bt, n0 + 128, 0, BBASE(0, 1));
  STAGE(A, m0 + 128, 0, ABASE(0, 1));
  STAGE(A, m0, 1, ABASE(1, 0));
  STAGE(Bt, n0, 1, BBASE(1, 0));
  STAGE(Bt, n0 + 128, 1, BBASE(1, 1));
  STAGE(A, m0 + 128, 1, ABASE(1, 1));
  WAITV(12);       // Ah0(0),Bh0(0) landed (12 newer instrs allowed in flight)
  PHASE_END

  // ---- main loop: d = 0..NT-3, steady waits {10, 12, 12}
#pragma unroll 1
  for (int d = 0; d <= NT - 3; ++d)
    TILE_BODY(d, 1, 10, 12, 12)

  // ---- peeled tails (no stages): d = NT-2 {10,8,4}, d = NT-1 {2,0,0}
  TILE_BODY(NT - 2, 0, 10, 8, 4)
  TILE_BODY(NT - 1, 0, 2, 0, 0)

  // ---- C write: row = m0 + ha*128 + wr2*64 + m*16 + kq*4 + j,
  //               col = n0 + hb*128 + wc4*32 + n*16 + fr
#pragma unroll
  for (int ra = 0; ra < 8; ++ra)
#pragma unroll
    for (int ca = 0; ca < 4; ++ca) {
      const int ha = ra >> 2, m = ra & 3;
      const int hb = ca >> 1, n = ca & 1;
      const int row0 = m0 + ha * 128 + wr2 * 64 + m * 16 + kq * 4;
      const int col  = n0 + hb * 128 + wc4 * 32 + n * 16 + fr;
      if (bz == 0) {
#pragma unroll
        for (int j = 0; j < 4; ++j)
          part0[(size_t)(row0 + j) * N + col] = acc[ra][ca][j];
      } else {
#pragma unroll
        for (int j = 0; j < 4; ++j)
          part1[(size_t)(row0 + j) * N + col] = f2bf(acc[ra][ca][j]);
      }
    }
}

// ---------------------------------------------------------------------------
// Kernel 4: out[i] = out[i] * (num0+num1) / (den0+den1)  (unchanged)
// ---------------------------------------------------------------------------
__global__ __launch_bounds__(256) void epilogue_kernel(
    const float* __restrict__ part0,
    const unsigned short* __restrict__ part1,
    float* __restrict__ out)
{
  const size_t total4 = (size_t)BB * CC * NN / 4;
  const f32x4* n0 = (const f32x4*)part0;
  const f32x4* d0 = n0 + total4;
  const uint2* n1 = (const uint2*)part1;
  const uint2* d1 = n1 + total4;
  f32x4* o4 = (f32x4*)out;
  const size_t stride = (size_t)gridDim.x * blockDim.x;
  for (size_t i = (size_t)blockIdx.x * blockDim.x + threadIdx.x; i < total4; i += stride) {
    const f32x4 a0 = n0[i], b0 = d0[i];
    const uint2 a1 = n1[i], b1 = d1[i];
    const f32x4 sg = o4[i];
    f32x4 r;
    r[0] = sg[0] * (a0[0] + bf2f((unsigned short)(a1.x & 0xffff))) /
                   (b0[0] + bf2f((unsigned short)(b1.x & 0xffff)));
    r[1] = sg[1] * (a0[1] + bf2f((unsigned short)(a1.x >> 16))) /
                   (b0[1] + bf2f((unsigned short)(b1.x >> 16)));
    r[2] = sg[2] * (a0[2] + bf2f((unsigned short)(a1.y & 0xffff))) /
                   (b0[2] + bf2f((unsigned short)(b1.y & 0xffff)));
    r[3] = sg[3] * (a0[3] + bf2f((unsigned short)(a1.y >> 16))) /
                   (b0[3] + bf2f((unsigned short)(b1.y >> 16)));
    o4[i] = r;
  }
}

// ---------------------------------------------------------------------------
// Workspace (96 MiB, unchanged layout):
//   [0, 16MiB)     : Abf  = bf16 [2048][4096]  (rows 0..1023 ekv, 1024..2047 ek)
//   [16MiB, 48MiB) : eBbf = bf16 [4096][4096]
//   [48MiB, 80MiB) : part0 = f32 [2048][4096] (z=0); v_bf aliases first 8MiB
//   [80MiB, 96MiB) : part1 = bf16 [2048][4096] (z=1)
//   sigmoid(q) lives in d_out (written by qkv, updated in place by epilogue).
// ---------------------------------------------------------------------------
extern "C" void kernel_launch(void* const* d_in, const int* in_sizes, int n_in,
                              void* d_out, int out_size, void* d_ws, size_t ws_size,
                              hipStream_t stream) {
  const float* x  = (const float*)d_in[0];
  const float* Wq = (const float*)d_in[1];
  const float* bq = (const float*)d_in[2];
  const float* Wk = (const float*)d_in[3];
  const float* bk = (const float*)d_in[4];
  const float* Wv = (const float*)d_in[5];
  const float* bv = (const float*)d_in[6];
  const float* pb = (const float*)d_in[7];
  float* out = (float*)d_out;

  char* ws = (char*)d_ws;
  unsigned short* Abf   = (unsigned short*)ws;
  unsigned short* eBbf  = (unsigned short*)(ws + (size_t)16777216);
  float*          part0 = (float*)(ws + (size_t)16777216 + 33554432);
  unsigned short* part1 = (unsigned short*)(ws + (size_t)16777216 + 33554432 + 33554432);

  unsigned short* ekv_bf = Abf;
  unsigned short* ek_bf  = Abf + (size_t)1024 * NN;
  unsigned short* v_bf   = (unsigned short*)part0;   // aliases part0 head (read before gemm)

  hipLaunchKernelGGL(qkv_mfma, dim3(NN / 128, 3, BB), dim3(256), 0, stream,
                     x, Wq, bq, Wk, bk, Wv, bv, out, ek_bf, v_bf);
  hipLaunchKernelGGL(ekv_kernel, dim3(1024), dim3(256), 0, stream,
                     ek_bf, v_bf, ekv_bf);
  hipLaunchKernelGGL(expb_kernel, dim3(2048), dim3(256), 0, stream, pb, eBbf);
  hipLaunchKernelGGL(gemm8p, dim3(8, 16, 2), dim3(512), 0, stream,
                     Abf, eBbf, part0, part1, NN, NN);
  hipLaunchKernelGGL(epilogue_kernel, dim3(2048), dim3(256), 0, stream,
                     part0, part1, out);
}